// Round 7
// baseline (226.739 us; speedup 1.0000x reference)
//
#include <hip/hip_runtime.h>
#include <hip/hip_cooperative_groups.h>

namespace cg = cooperative_groups;

#define N 8192
#define H 256
#define TOPK 16
#define NSEC 11
#define NEG_SLOPE 0.2
#define NB 256                 // blocks (one per CU; co-resident for coop launch)
#define NT 256                 // threads per block
#define RPB (N / NB)           // 32 rows per block
#define CAP 1024               // LDS candidate capacity per sector (+34 sigma)
#define IDX_SENT 0x7fffffff

__device__ __forceinline__ bool better(double av, int ai, double bv, int bi) {
    return (av > bv) || (av == bv && ai < bi);
}

__global__ __launch_bounds__(NT) void fused_all(
    const float* __restrict__ E, const float* __restrict__ W,
    const float* __restrict__ a, const int* __restrict__ sec,
    const int* __restrict__ act,
    float* __restrict__ s1f, double* __restrict__ s2g,
    int* __restrict__ top_idx, int* __restrict__ fill_idx,
    int* __restrict__ m_arr, float* __restrict__ out)
{
    cg::grid_group grid = cg::this_grid();

    __shared__ double sv1[H];
    __shared__ double sv2[H];
    __shared__ double kv[CAP];   // phase-C candidate values (also fallback scratch)
    __shared__ int ki[CAP];      // phase-C candidate indices
    __shared__ int s_cnt;

    int t = threadIdx.x;
    int blk = blockIdx.x;
    int lane = t & 63;
    int w = t >> 6;  // wave 0..3

    // ---- phase A: v1 = W^T a1, v2 = W^T a2 (redundant per block, f64) ----
    {
        double acc1 = 0.0, acc2 = 0.0;
        for (int j = 0; j < H; ++j) {
            double wv = (double)W[j * H + t];   // coalesced across t
            acc1 += wv * (double)a[j];
            acc2 += wv * (double)a[H + j];
        }
        sv1[t] = acc1;
        sv2[t] = acc2;
    }
    __syncthreads();

    // ---- phase B: s1/s2 for rows [blk*32, blk*32+32), wave-per-row ----
    for (int q = 0; q < RPB / 4; ++q) {
        int r_loc = w + 4 * q;                 // 0..31
        int row = blk * RPB + r_loc;
        const float4* Erow = (const float4*)(E + (size_t)row * H);
        float4 e = Erow[lane];
        int base = lane * 4;
        double acc1 = (double)e.x * sv1[base + 0] + (double)e.y * sv1[base + 1] +
                      (double)e.z * sv1[base + 2] + (double)e.w * sv1[base + 3];
        double acc2 = (double)e.x * sv2[base + 0] + (double)e.y * sv2[base + 1] +
                      (double)e.z * sv2[base + 2] + (double)e.w * sv2[base + 3];
        for (int o = 32; o > 0; o >>= 1) {
            acc1 += __shfl_down(acc1, o);
            acc2 += __shfl_down(acc2, o);
        }
        if (lane == 0) {
            s1f[row] = (float)acc1;
            s2g[row] = acc2;                   // f64 ordering key
        }
    }

    grid.sync();

    // ---- phase C: blocks 0..NSEC-1 do per-sector top-16 + m + fill ----
    if (blk < NSEC) {
        int c = blk;
        if (t == 0) s_cnt = 0;
        __syncthreads();

        // LDS compaction of sector members (ballot + LDS atomic per wave)
        for (int j = t; j < N; j += NT) {
            bool pred = (act[j] != 0) && (sec[j] == c);
            unsigned long long mask = __ballot(pred);
            int nact = __popcll(mask);
            if (nact > 0) {
                int leader = (int)__ffsll(mask) - 1;
                int b = 0;
                if (lane == leader) b = atomicAdd(&s_cnt, nact);
                b = __shfl(b, leader);
                if (pred) {
                    int pos = b + __popcll(mask & ((1ull << lane) - 1));
                    if (pos < CAP) {
                        kv[pos] = s2g[j];
                        ki[pos] = j;
                    }
                }
            }
        }
        __syncthreads();
        int total = s_cnt;

        if (total <= CAP) {
            if (w == 0) {
                // wave 0: 16 rounds of argmax over CAP slots (16 per lane)
                double cv[CAP / 64];
                int ci[CAP / 64];
                for (int p = 0; p < CAP / 64; ++p) {
                    int slot = p * 64 + lane;
                    bool ok = (slot < total);
                    cv[p] = ok ? kv[slot] : -INFINITY;
                    ci[p] = ok ? ki[slot] : IDX_SENT;
                }
                for (int r = 0; r < TOPK; ++r) {
                    double bv = cv[0];
                    int bi = ci[0];
                    for (int p = 1; p < CAP / 64; ++p)
                        if (better(cv[p], ci[p], bv, bi)) { bv = cv[p]; bi = ci[p]; }
                    for (int o = 32; o > 0; o >>= 1) {
                        double ov = __shfl_xor(bv, o);
                        int oi = __shfl_xor(bi, o);
                        if (better(ov, oi, bv, bi)) { bv = ov; bi = oi; }
                    }
                    if (bi != IDX_SENT) {
                        for (int p = 0; p < CAP / 64; ++p)
                            if (ci[p] == bi) { cv[p] = -INFINITY; ci[p] = IDX_SENT; }
                    }
                    if (lane == 0) top_idx[c * TOPK + r] = (bi == IDX_SENT) ? -1 : bi;
                }
                if (lane == 0) m_arr[c] = (total < TOPK) ? total : TOPK;
            }
            if (w == 1) {
                // wave 1: fill indices = first 16 j failing the predicate
                int cnt2 = 0;
                for (int basej = 0; basej < N && cnt2 < TOPK; basej += 64) {
                    int j = basej + lane;
                    bool fail = !((act[j] != 0) && (sec[j] == c));
                    unsigned long long mask = __ballot(fail);
                    if (fail) {
                        int rank = cnt2 + __popcll(mask & ((1ull << lane) - 1));
                        if (rank < TOPK) fill_idx[c * TOPK + rank] = j;
                    }
                    cnt2 += __popcll(mask);
                }
            }
        } else {
            // fallback (unreachable for this input): 16-round block argmax
            double last_v = INFINITY;
            int last_i = -1;
            for (int r = 0; r < TOPK; ++r) {
                double bv = -INFINITY;
                int bi = IDX_SENT;
                for (int j = t; j < N; j += NT) {
                    if (act[j] != 0 && sec[j] == c) {
                        double v = s2g[j];
                        bool worse = (v < last_v) || (v == last_v && j > last_i);
                        if (worse && better(v, j, bv, bi)) { bv = v; bi = j; }
                    }
                }
                kv[t] = bv;
                ki[t] = bi;
                __syncthreads();
                for (int s = 128; s > 0; s >>= 1) {
                    if (t < s) {
                        if (better(kv[t + s], ki[t + s], kv[t], ki[t])) {
                            kv[t] = kv[t + s];
                            ki[t] = ki[t + s];
                        }
                    }
                    __syncthreads();
                }
                last_v = kv[0];
                last_i = ki[0];
                if (t == 0) top_idx[c * TOPK + r] = (last_i == IDX_SENT) ? -1 : last_i;
                __syncthreads();  // protect kv[0]/ki[0] reads before next round
            }
            if (t == 0) m_arr[c] = (total < TOPK) ? total : TOPK;
            if (w == 1) {
                int cnt2 = 0;
                for (int basej = 0; basej < N && cnt2 < TOPK; basej += 64) {
                    int j = basej + lane;
                    bool fail = !((act[j] != 0) && (sec[j] == c));
                    unsigned long long mask = __ballot(fail);
                    if (fail) {
                        int rank = cnt2 + __popcll(mask & ((1ull << lane) - 1));
                        if (rank < TOPK) fill_idx[c * TOPK + rank] = j;
                    }
                    cnt2 += __popcll(mask);
                }
            }
        }
    }

    grid.sync();

    // ---- phase D: outputs; this block covers rows [blk*32, blk*32+32) ----
    for (int u = 0; u < 2; ++u) {
        int gid = blk * (RPB * TOPK) + u * NT + t;   // 512 per block
        int i = gid >> 4;
        int slot = gid & 15;

        float wgt = 0.0f;
        float fidx;
        float fvalid = 0.0f;

        if (act[i] == 0) {
            fidx = (float)slot;  // all -inf row: stable top_k -> indices 0..15
        } else {
            int c = sec[i];
            int m = m_arr[c];
            if (slot < m) {
                int j = top_idx[c * TOPK + slot];
                double x = (double)s1f[i] + s2g[j];
                double attv = (x >= 0.0) ? x : NEG_SLOPE * x;
                wgt = (float)attv;
                fvalid = 1.0f;
                fidx = (float)j;
            } else {
                fidx = (float)fill_idx[c * TOPK + (slot - m)];
            }
        }

        out[gid] = wgt;
        out[N * TOPK + gid] = fidx;
        out[2 * N * TOPK + gid] = fvalid;
    }
}

extern "C" void kernel_launch(void* const* d_in, const int* in_sizes, int n_in,
                              void* d_out, int out_size, void* d_ws, size_t ws_size,
                              hipStream_t stream) {
    const float* E = (const float*)d_in[0];
    const float* W = (const float*)d_in[1];
    const float* a = (const float*)d_in[2];
    const int* sec = (const int*)d_in[3];
    const int* act = (const int*)d_in[4];  // bool input uploaded as int32

    // workspace (~98 KB, 8-byte-aligned first)
    char* ws = (char*)d_ws;
    double* s2g = (double*)ws;                 // N f64
    float* s1f = (float*)(s2g + N);            // N f32
    int* top_idx = (int*)(s1f + N);            // NSEC*TOPK
    int* fill_idx = top_idx + NSEC * TOPK;     // NSEC*TOPK
    int* m_arr = fill_idx + NSEC * TOPK;       // NSEC

    float* out = (float*)d_out;

    void* args[] = { (void*)&E, (void*)&W, (void*)&a, (void*)&sec, (void*)&act,
                     (void*)&s1f, (void*)&s2g, (void*)&top_idx, (void*)&fill_idx,
                     (void*)&m_arr, (void*)&out };
    hipLaunchCooperativeKernel(reinterpret_cast<void*>(fused_all),
                               dim3(NB), dim3(NT), args, 0, stream);
}

// Round 8
// 168.257 us; speedup vs baseline: 1.3476x; 1.3476x over previous
//
#include <hip/hip_runtime.h>

#define N 8192
#define H 256
#define TOPK 16
#define NSEC 11
#define NEG_SLOPE 0.2
#define NB 256                 // K1 blocks (one per CU)
#define NT 256                 // threads per block
#define RPB (N / NB)           // 32 rows per block
#define CAP 1024               // K2 LDS candidate capacity (+34 sigma vs ~372)
#define IDX_SENT 0x7fffffff

__device__ __forceinline__ bool better(double av, int ai, double bv, int bi) {
    return (av > bv) || (av == bv && ai < bi);
}

// ---------------------------------------------------------------------------
// K1: redundant v = W^T a per block (4 independent f64 chains, 4 loads in
// flight, a[] in LDS), then s1/s2 for this block's 32 rows (wave-per-row,
// float4 loads, f64 accumulate + shuffle reduce — R6-proven numerics).
// ---------------------------------------------------------------------------
__global__ __launch_bounds__(NT) void compute_v_s(
    const float* __restrict__ E, const float* __restrict__ W,
    const float* __restrict__ a,
    float* __restrict__ s1f, double* __restrict__ s2g)
{
    __shared__ float sa[2 * H];
    __shared__ double sv1[H];
    __shared__ double sv2[H];

    int t = threadIdx.x;
    int blk = blockIdx.x;
    int lane = t & 63;
    int w = t >> 6;  // wave 0..3

    sa[t] = a[t];
    sa[t + H] = a[t + H];
    __syncthreads();

    // ---- phase A: thread t owns column t; 4 independent chains ----
    {
        double a1_0 = 0.0, a1_1 = 0.0, a1_2 = 0.0, a1_3 = 0.0;
        double a2_0 = 0.0, a2_1 = 0.0, a2_2 = 0.0, a2_3 = 0.0;
        for (int j = 0; j < H; j += 4) {
            double w0 = (double)W[(j + 0) * H + t];
            double w1 = (double)W[(j + 1) * H + t];
            double w2 = (double)W[(j + 2) * H + t];
            double w3 = (double)W[(j + 3) * H + t];
            a1_0 += w0 * (double)sa[j + 0];
            a1_1 += w1 * (double)sa[j + 1];
            a1_2 += w2 * (double)sa[j + 2];
            a1_3 += w3 * (double)sa[j + 3];
            a2_0 += w0 * (double)sa[H + j + 0];
            a2_1 += w1 * (double)sa[H + j + 1];
            a2_2 += w2 * (double)sa[H + j + 2];
            a2_3 += w3 * (double)sa[H + j + 3];
        }
        sv1[t] = (a1_0 + a1_1) + (a1_2 + a1_3);
        sv2[t] = (a2_0 + a2_1) + (a2_2 + a2_3);
    }
    __syncthreads();

    // ---- phase B: rows [blk*32, blk*32+32), wave-per-row ----
    for (int q = 0; q < RPB / 4; ++q) {
        int r_loc = w + 4 * q;                 // 0..31
        int row = blk * RPB + r_loc;
        const float4* Erow = (const float4*)(E + (size_t)row * H);
        float4 e = Erow[lane];
        int base = lane * 4;
        double acc1 = (double)e.x * sv1[base + 0] + (double)e.y * sv1[base + 1] +
                      (double)e.z * sv1[base + 2] + (double)e.w * sv1[base + 3];
        double acc2 = (double)e.x * sv2[base + 0] + (double)e.y * sv2[base + 1] +
                      (double)e.z * sv2[base + 2] + (double)e.w * sv2[base + 3];
        for (int o = 32; o > 0; o >>= 1) {
            acc1 += __shfl_down(acc1, o);
            acc2 += __shfl_down(acc2, o);
        }
        if (lane == 0) {
            s1f[row] = (float)acc1;
            s2g[row] = acc2;                   // f64 ordering key
        }
    }
}

// ---------------------------------------------------------------------------
// K2: block per sector. LDS ballot compaction of sector members, wave 0 does
// 16-round register argmax over <=CAP entries, wave 1 computes fill indices.
// Block-wide fallback keeps correctness unconditional if CAP overflows.
// ---------------------------------------------------------------------------
__global__ __launch_bounds__(NT) void topk_sector(
    const double* __restrict__ s2g, const int* __restrict__ sec,
    const int* __restrict__ act,
    int* __restrict__ top_idx, int* __restrict__ fill_idx,
    int* __restrict__ m_arr)
{
    __shared__ double kv[CAP];
    __shared__ int ki[CAP];
    __shared__ int s_cnt;

    int c = blockIdx.x;
    int t = threadIdx.x;
    int lane = t & 63;
    int w = t >> 6;

    if (t == 0) s_cnt = 0;
    __syncthreads();

    for (int j = t; j < N; j += NT) {
        bool pred = (act[j] != 0) && (sec[j] == c);
        unsigned long long mask = __ballot(pred);
        int nact = __popcll(mask);
        if (nact > 0) {
            int leader = (int)__ffsll(mask) - 1;
            int b = 0;
            if (lane == leader) b = atomicAdd(&s_cnt, nact);
            b = __shfl(b, leader);
            if (pred) {
                int pos = b + __popcll(mask & ((1ull << lane) - 1));
                if (pos < CAP) {
                    kv[pos] = s2g[j];
                    ki[pos] = j;
                }
            }
        }
    }
    __syncthreads();
    int total = s_cnt;

    if (total <= CAP) {
        if (w == 0) {
            double cv[CAP / 64];
            int ci[CAP / 64];
            for (int p = 0; p < CAP / 64; ++p) {
                int slot = p * 64 + lane;
                bool ok = (slot < total);
                cv[p] = ok ? kv[slot] : -INFINITY;
                ci[p] = ok ? ki[slot] : IDX_SENT;
            }
            for (int r = 0; r < TOPK; ++r) {
                double bv = cv[0];
                int bi = ci[0];
                for (int p = 1; p < CAP / 64; ++p)
                    if (better(cv[p], ci[p], bv, bi)) { bv = cv[p]; bi = ci[p]; }
                for (int o = 32; o > 0; o >>= 1) {
                    double ov = __shfl_xor(bv, o);
                    int oi = __shfl_xor(bi, o);
                    if (better(ov, oi, bv, bi)) { bv = ov; bi = oi; }
                }
                if (bi != IDX_SENT) {
                    for (int p = 0; p < CAP / 64; ++p)
                        if (ci[p] == bi) { cv[p] = -INFINITY; ci[p] = IDX_SENT; }
                }
                if (lane == 0) top_idx[c * TOPK + r] = (bi == IDX_SENT) ? -1 : bi;
            }
            if (lane == 0) m_arr[c] = (total < TOPK) ? total : TOPK;
        }
        if (w == 1) {
            int cnt2 = 0;
            for (int basej = 0; basej < N && cnt2 < TOPK; basej += 64) {
                int j = basej + lane;
                bool fail = !((act[j] != 0) && (sec[j] == c));
                unsigned long long mask = __ballot(fail);
                if (fail) {
                    int rank = cnt2 + __popcll(mask & ((1ull << lane) - 1));
                    if (rank < TOPK) fill_idx[c * TOPK + rank] = j;
                }
                cnt2 += __popcll(mask);
            }
        }
    } else {
        // fallback (unreachable for this input): 16-round block argmax
        double last_v = INFINITY;
        int last_i = -1;
        for (int r = 0; r < TOPK; ++r) {
            double bv = -INFINITY;
            int bi = IDX_SENT;
            for (int j = t; j < N; j += NT) {
                if (act[j] != 0 && sec[j] == c) {
                    double v = s2g[j];
                    bool worse = (v < last_v) || (v == last_v && j > last_i);
                    if (worse && better(v, j, bv, bi)) { bv = v; bi = j; }
                }
            }
            kv[t] = bv;
            ki[t] = bi;
            __syncthreads();
            for (int s = 128; s > 0; s >>= 1) {
                if (t < s) {
                    if (better(kv[t + s], ki[t + s], kv[t], ki[t])) {
                        kv[t] = kv[t + s];
                        ki[t] = ki[t + s];
                    }
                }
                __syncthreads();
            }
            last_v = kv[0];
            last_i = ki[0];
            if (t == 0) top_idx[c * TOPK + r] = (last_i == IDX_SENT) ? -1 : last_i;
            __syncthreads();
        }
        if (t == 0) m_arr[c] = (total < TOPK) ? total : TOPK;
        if (w == 1) {
            int cnt2 = 0;
            for (int basej = 0; basej < N && cnt2 < TOPK; basej += 64) {
                int j = basej + lane;
                bool fail = !((act[j] != 0) && (sec[j] == c));
                unsigned long long mask = __ballot(fail);
                if (fail) {
                    int rank = cnt2 + __popcll(mask & ((1ull << lane) - 1));
                    if (rank < TOPK) fill_idx[c * TOPK + rank] = j;
                }
                cnt2 += __popcll(mask);
            }
        }
    }
}

// ---------------------------------------------------------------------------
// K3: write outputs (weight, index-as-float, valid-as-float planes).
// ---------------------------------------------------------------------------
__global__ __launch_bounds__(NT) void write_out(const float* __restrict__ s1f,
                                                const double* __restrict__ s2g,
                                                const int* __restrict__ sec,
                                                const int* __restrict__ act,
                                                const int* __restrict__ top_idx,
                                                const int* __restrict__ fill_idx,
                                                const int* __restrict__ m_arr,
                                                float* __restrict__ out) {
    int gid = blockIdx.x * NT + threadIdx.x;  // N*TOPK total
    int i = gid >> 4;
    int slot = gid & 15;

    float wgt = 0.0f;
    float fidx;
    float fvalid = 0.0f;

    if (act[i] == 0) {
        fidx = (float)slot;  // all -inf row: stable top_k -> indices 0..15
    } else {
        int c = sec[i];
        int m = m_arr[c];
        if (slot < m) {
            int j = top_idx[c * TOPK + slot];
            double x = (double)s1f[i] + s2g[j];
            double attv = (x >= 0.0) ? x : NEG_SLOPE * x;
            wgt = (float)attv;
            fvalid = 1.0f;
            fidx = (float)j;
        } else {
            fidx = (float)fill_idx[c * TOPK + (slot - m)];
        }
    }

    out[gid] = wgt;
    out[N * TOPK + gid] = fidx;
    out[2 * N * TOPK + gid] = fvalid;
}

extern "C" void kernel_launch(void* const* d_in, const int* in_sizes, int n_in,
                              void* d_out, int out_size, void* d_ws, size_t ws_size,
                              hipStream_t stream) {
    const float* E = (const float*)d_in[0];
    const float* W = (const float*)d_in[1];
    const float* a = (const float*)d_in[2];
    const int* sec = (const int*)d_in[3];
    const int* act = (const int*)d_in[4];  // bool input uploaded as int32

    // workspace (~97 KB, 8-byte-aligned first)
    char* ws = (char*)d_ws;
    double* s2g = (double*)ws;                 // N f64
    float* s1f = (float*)(s2g + N);            // N f32
    int* top_idx = (int*)(s1f + N);            // NSEC*TOPK
    int* fill_idx = top_idx + NSEC * TOPK;     // NSEC*TOPK
    int* m_arr = fill_idx + NSEC * TOPK;       // NSEC

    float* out = (float*)d_out;

    hipLaunchKernelGGL(compute_v_s, dim3(NB), dim3(NT), 0, stream,
                       E, W, a, s1f, s2g);
    hipLaunchKernelGGL(topk_sector, dim3(NSEC), dim3(NT), 0, stream,
                       s2g, sec, act, top_idx, fill_idx, m_arr);
    hipLaunchKernelGGL(write_out, dim3((N * TOPK) / NT), dim3(NT), 0, stream,
                       s1f, s2g, sec, act, top_idx, fill_idx, m_arr, out);
}

// Round 9
// 145.382 us; speedup vs baseline: 1.5596x; 1.1573x over previous
//
#include <hip/hip_runtime.h>

#define N 8192
#define H 256
#define TOPK 16
#define NSEC 11
#define NEG_SLOPE 0.2
#define NB 256                 // K1 blocks (one per CU)
#define NT 256                 // threads per block
#define CAP 1024               // K2 LDS candidate capacity (+34 sigma vs ~372)
#define RPB (N / NB)           // 32 rows per block
#define IDX_SENT 0x7fffffff

__device__ __forceinline__ bool better(double av, int ai, double bv, int bi) {
    return (av > bv) || (av == bv && ai < bi);
}

// ---------------------------------------------------------------------------
// K1: redundant v = W^T a per block (4 independent f64 chains), then s1/s2
// for this block's 32 rows (wave-per-row, float4 loads, f64 accumulate +
// shuffle reduce — R6/R8-proven numerics).
// ---------------------------------------------------------------------------
__global__ __launch_bounds__(NT) void compute_v_s(
    const float* __restrict__ E, const float* __restrict__ W,
    const float* __restrict__ a,
    float* __restrict__ s1f, double* __restrict__ s2g)
{
    __shared__ float sa[2 * H];
    __shared__ double sv1[H];
    __shared__ double sv2[H];

    int t = threadIdx.x;
    int blk = blockIdx.x;
    int lane = t & 63;
    int w = t >> 6;  // wave 0..3

    sa[t] = a[t];
    sa[t + H] = a[t + H];
    __syncthreads();

    // ---- phase A: thread t owns column t; 4 independent chains ----
    {
        double a1_0 = 0.0, a1_1 = 0.0, a1_2 = 0.0, a1_3 = 0.0;
        double a2_0 = 0.0, a2_1 = 0.0, a2_2 = 0.0, a2_3 = 0.0;
        for (int j = 0; j < H; j += 4) {
            double w0 = (double)W[(j + 0) * H + t];
            double w1 = (double)W[(j + 1) * H + t];
            double w2 = (double)W[(j + 2) * H + t];
            double w3 = (double)W[(j + 3) * H + t];
            a1_0 += w0 * (double)sa[j + 0];
            a1_1 += w1 * (double)sa[j + 1];
            a1_2 += w2 * (double)sa[j + 2];
            a1_3 += w3 * (double)sa[j + 3];
            a2_0 += w0 * (double)sa[H + j + 0];
            a2_1 += w1 * (double)sa[H + j + 1];
            a2_2 += w2 * (double)sa[H + j + 2];
            a2_3 += w3 * (double)sa[H + j + 3];
        }
        sv1[t] = (a1_0 + a1_1) + (a1_2 + a1_3);
        sv2[t] = (a2_0 + a2_1) + (a2_2 + a2_3);
    }
    __syncthreads();

    // ---- phase B: rows [blk*32, blk*32+32), wave-per-row ----
    for (int q = 0; q < RPB / 4; ++q) {
        int r_loc = w + 4 * q;                 // 0..31
        int row = blk * RPB + r_loc;
        const float4* Erow = (const float4*)(E + (size_t)row * H);
        float4 e = Erow[lane];
        int base = lane * 4;
        double acc1 = (double)e.x * sv1[base + 0] + (double)e.y * sv1[base + 1] +
                      (double)e.z * sv1[base + 2] + (double)e.w * sv1[base + 3];
        double acc2 = (double)e.x * sv2[base + 0] + (double)e.y * sv2[base + 1] +
                      (double)e.z * sv2[base + 2] + (double)e.w * sv2[base + 3];
        for (int o = 32; o > 0; o >>= 1) {
            acc1 += __shfl_down(acc1, o);
            acc2 += __shfl_down(acc2, o);
        }
        if (lane == 0) {
            s1f[row] = (float)acc1;
            s2g[row] = acc2;                   // f64 ordering key
        }
    }
}

// ---------------------------------------------------------------------------
// K2: block per sector. Latency-batched compaction:
//   (1) 16 independent int4 loads/thread bring all act+sec in one round,
//   (2) predicate bitmask -> one LDS atomicAdd/thread, indices to LDS,
//   (3) one parallel gather round kv[p] = s2g[ki[p]].
// Then wave 0: 16-round register argmax; wave 1: fill indices.
// Unconditional fallback if CAP overflows (never for this input).
// ---------------------------------------------------------------------------
__global__ __launch_bounds__(NT) void topk_sector(
    const double* __restrict__ s2g, const int* __restrict__ sec,
    const int* __restrict__ act,
    int* __restrict__ top_idx, int* __restrict__ fill_idx,
    int* __restrict__ m_arr)
{
    __shared__ double kv[CAP];
    __shared__ int ki[CAP];
    __shared__ int s_cnt;

    int c = blockIdx.x;
    int t = threadIdx.x;
    int lane = t & 63;
    int w = t >> 6;

    if (t == 0) s_cnt = 0;
    __syncthreads();

    // (1) batched loads: thread t covers j = 4t + 1024k + e, k=0..7, e=0..3
    int4 av[8], sv[8];
    const int4* act4 = (const int4*)act;
    const int4* sec4 = (const int4*)sec;
#pragma unroll
    for (int k = 0; k < 8; ++k) {
        av[k] = act4[t + k * 256];
        sv[k] = sec4[t + k * 256];
    }

    // (2) predicate bitmask + compaction of indices
    unsigned pm = 0;
#pragma unroll
    for (int k = 0; k < 8; ++k) {
        if (av[k].x != 0 && sv[k].x == c) pm |= 1u << (4 * k + 0);
        if (av[k].y != 0 && sv[k].y == c) pm |= 1u << (4 * k + 1);
        if (av[k].z != 0 && sv[k].z == c) pm |= 1u << (4 * k + 2);
        if (av[k].w != 0 && sv[k].w == c) pm |= 1u << (4 * k + 3);
    }
    int mycnt = __popc(pm);
    int base = 0;
    if (mycnt > 0) base = atomicAdd(&s_cnt, mycnt);
    {
        unsigned rem = pm;
        int pos = base;
        while (rem) {
            int e = __ffs(rem) - 1;
            rem &= rem - 1;
            if (pos < CAP) ki[pos] = 4 * t + 1024 * (e >> 2) + (e & 3);
            ++pos;
        }
    }
    __syncthreads();
    int total = s_cnt;

    // (3) parallel value gather
    for (int p = t; p < total && p < CAP; p += NT) kv[p] = s2g[ki[p]];
    __syncthreads();

    if (total <= CAP) {
        if (w == 0) {
            double cv[CAP / 64];
            int ci[CAP / 64];
            for (int p = 0; p < CAP / 64; ++p) {
                int slot = p * 64 + lane;
                bool ok = (slot < total);
                cv[p] = ok ? kv[slot] : -INFINITY;
                ci[p] = ok ? ki[slot] : IDX_SENT;
            }
            for (int r = 0; r < TOPK; ++r) {
                double bv = cv[0];
                int bi = ci[0];
                for (int p = 1; p < CAP / 64; ++p)
                    if (better(cv[p], ci[p], bv, bi)) { bv = cv[p]; bi = ci[p]; }
                for (int o = 32; o > 0; o >>= 1) {
                    double ov = __shfl_xor(bv, o);
                    int oi = __shfl_xor(bi, o);
                    if (better(ov, oi, bv, bi)) { bv = ov; bi = oi; }
                }
                if (bi != IDX_SENT) {
                    for (int p = 0; p < CAP / 64; ++p)
                        if (ci[p] == bi) { cv[p] = -INFINITY; ci[p] = IDX_SENT; }
                }
                if (lane == 0) top_idx[c * TOPK + r] = (bi == IDX_SENT) ? -1 : bi;
            }
            if (lane == 0) m_arr[c] = (total < TOPK) ? total : TOPK;
        }
        if (w == 1) {
            // fill indices = first 16 j failing the predicate (L1-hot by now)
            int cnt2 = 0;
            for (int basej = 0; basej < N && cnt2 < TOPK; basej += 64) {
                int j = basej + lane;
                bool fail = !((act[j] != 0) && (sec[j] == c));
                unsigned long long mask = __ballot(fail);
                if (fail) {
                    int rank = cnt2 + __popcll(mask & ((1ull << lane) - 1));
                    if (rank < TOPK) fill_idx[c * TOPK + rank] = j;
                }
                cnt2 += __popcll(mask);
            }
        }
    } else {
        // fallback (unreachable for this input): 16-round block argmax
        double last_v = INFINITY;
        int last_i = -1;
        for (int r = 0; r < TOPK; ++r) {
            double bv = -INFINITY;
            int bi = IDX_SENT;
            for (int j = t; j < N; j += NT) {
                if (act[j] != 0 && sec[j] == c) {
                    double v = s2g[j];
                    bool worse = (v < last_v) || (v == last_v && j > last_i);
                    if (worse && better(v, j, bv, bi)) { bv = v; bi = j; }
                }
            }
            kv[t] = bv;
            ki[t] = bi;
            __syncthreads();
            for (int s = 128; s > 0; s >>= 1) {
                if (t < s) {
                    if (better(kv[t + s], ki[t + s], kv[t], ki[t])) {
                        kv[t] = kv[t + s];
                        ki[t] = ki[t + s];
                    }
                }
                __syncthreads();
            }
            last_v = kv[0];
            last_i = ki[0];
            if (t == 0) top_idx[c * TOPK + r] = (last_i == IDX_SENT) ? -1 : last_i;
            __syncthreads();
        }
        if (t == 0) m_arr[c] = (total < TOPK) ? total : TOPK;
        if (w == 1) {
            int cnt2 = 0;
            for (int basej = 0; basej < N && cnt2 < TOPK; basej += 64) {
                int j = basej + lane;
                bool fail = !((act[j] != 0) && (sec[j] == c));
                unsigned long long mask = __ballot(fail);
                if (fail) {
                    int rank = cnt2 + __popcll(mask & ((1ull << lane) - 1));
                    if (rank < TOPK) fill_idx[c * TOPK + rank] = j;
                }
                cnt2 += __popcll(mask);
            }
        }
    }
}

// ---------------------------------------------------------------------------
// K3: write outputs (weight, index-as-float, valid-as-float planes).
// ---------------------------------------------------------------------------
__global__ __launch_bounds__(NT) void write_out(const float* __restrict__ s1f,
                                                const double* __restrict__ s2g,
                                                const int* __restrict__ sec,
                                                const int* __restrict__ act,
                                                const int* __restrict__ top_idx,
                                                const int* __restrict__ fill_idx,
                                                const int* __restrict__ m_arr,
                                                float* __restrict__ out) {
    int gid = blockIdx.x * NT + threadIdx.x;  // N*TOPK total
    int i = gid >> 4;
    int slot = gid & 15;

    float wgt = 0.0f;
    float fidx;
    float fvalid = 0.0f;

    if (act[i] == 0) {
        fidx = (float)slot;  // all -inf row: stable top_k -> indices 0..15
    } else {
        int c = sec[i];
        int m = m_arr[c];
        if (slot < m) {
            int j = top_idx[c * TOPK + slot];
            double x = (double)s1f[i] + s2g[j];
            double attv = (x >= 0.0) ? x : NEG_SLOPE * x;
            wgt = (float)attv;
            fvalid = 1.0f;
            fidx = (float)j;
        } else {
            fidx = (float)fill_idx[c * TOPK + (slot - m)];
        }
    }

    out[gid] = wgt;
    out[N * TOPK + gid] = fidx;
    out[2 * N * TOPK + gid] = fvalid;
}

extern "C" void kernel_launch(void* const* d_in, const int* in_sizes, int n_in,
                              void* d_out, int out_size, void* d_ws, size_t ws_size,
                              hipStream_t stream) {
    const float* E = (const float*)d_in[0];
    const float* W = (const float*)d_in[1];
    const float* a = (const float*)d_in[2];
    const int* sec = (const int*)d_in[3];
    const int* act = (const int*)d_in[4];  // bool input uploaded as int32

    // workspace (~97 KB, 8-byte-aligned first) — proven size range
    char* ws = (char*)d_ws;
    double* s2g = (double*)ws;                 // N f64
    float* s1f = (float*)(s2g + N);            // N f32
    int* top_idx = (int*)(s1f + N);            // NSEC*TOPK
    int* fill_idx = top_idx + NSEC * TOPK;     // NSEC*TOPK
    int* m_arr = fill_idx + NSEC * TOPK;       // NSEC

    float* out = (float*)d_out;

    hipLaunchKernelGGL(compute_v_s, dim3(NB), dim3(NT), 0, stream,
                       E, W, a, s1f, s2g);
    hipLaunchKernelGGL(topk_sector, dim3(NSEC), dim3(NT), 0, stream,
                       s2g, sec, act, top_idx, fill_idx, m_arr);
    hipLaunchKernelGGL(write_out, dim3((N * TOPK) / NT), dim3(NT), 0, stream,
                       s1f, s2g, sec, act, top_idx, fill_idx, m_arr, out);
}